// Round 2
// baseline (541.754 us; speedup 1.0000x reference)
//
#include <hip/hip_runtime.h>
#include <hip/hip_bf16.h>

#define B_  2
#define D_  256
#define H_  8
#define T_  128
#define S_  128
#define F_  64
#define C_  512
#define TE_ 512

typedef _Float16 f16x8 __attribute__((ext_vector_type(8)));
typedef _Float16 f16x4 __attribute__((ext_vector_type(4)));
typedef float    f32x4 __attribute__((ext_vector_type(4)));

// ---------------------------------------------------------------------------
// K1: time_proj[b*T+t][c] = temb[b,t,:] @ w_time[:,c] + b_time[c] + b_dist[c]
// 128 blocks x 256 threads, 2 rows per block (shares the w_time stream).
// ---------------------------------------------------------------------------
__global__ __launch_bounds__(256) void k_time_proj(
    const float* __restrict__ temb, const float* __restrict__ w_time,
    const float* __restrict__ b_time, const float* __restrict__ b_dist,
    float* __restrict__ tp)
{
    int row0 = blockIdx.x * 2;
    int tid  = threadIdx.x;
    __shared__ float te[2][TE_];
    for (int i = tid; i < 2 * TE_; i += 256)
        te[i >> 9][i & 511] = temb[(size_t)row0 * TE_ + i];
    __syncthreads();
    for (int half = 0; half < 2; ++half) {
        int c = tid + half * 256;
        float bias = b_time[c] + b_dist[c];
        float a0 = bias, a1 = bias;
        for (int e = 0; e < TE_; ++e) {
            float w = w_time[(size_t)e * C_ + c];
            a0 += te[0][e] * w;
            a1 += te[1][e] * w;
        }
        tp[(size_t)row0 * C_ + c]       = a0;
        tp[(size_t)(row0 + 1) * C_ + c] = a1;
    }
}

// ---------------------------------------------------------------------------
// K2: Wt[n][k] = f16(w_out[k][n])  via LDS 64x64 transpose (coalesced both ways)
// grid (8,8) x 256 threads
// ---------------------------------------------------------------------------
__global__ __launch_bounds__(256) void k_wt(
    const float* __restrict__ w_out, _Float16* __restrict__ Wt)
{
    __shared__ float tile[64][65];
    int bn = blockIdx.x;   // n tile
    int bk = blockIdx.y;   // k tile
    int tx = threadIdx.x & 63;
    int ty = threadIdx.x >> 6;   // 0..3
#pragma unroll
    for (int p = 0; p < 16; ++p) {
        int row = p * 4 + ty;    // k-local
        tile[row][tx] = w_out[(size_t)(bk * 64 + row) * C_ + bn * 64 + tx];
    }
    __syncthreads();
#pragma unroll
    for (int p = 0; p < 16; ++p) {
        int row = p * 4 + ty;    // n-local
        Wt[(size_t)(bn * 64 + row) * C_ + bk * 64 + tx] = (_Float16)tile[tx][row];
    }
}

// ---------------------------------------------------------------------------
// K3 (fused embed+silu+GEMM):
// R[(bt*S+s)][n] = silu( tp[bt][k] + f0(s)*w0[k] + f1(s)*w1[k] + f2(s)*w2[k] ) @ Wt + b_out
// grid (bm=256 (=bt), bn=4), 256 threads, 4 waves 2x2, mfma_f32_16x16x32_f16.
// A-tile generated in LDS on the fly (rank-3 outer product + silu).
// ---------------------------------------------------------------------------
__global__ __launch_bounds__(256) void k_rpe_gemm(
    const float* __restrict__ tp, const int* __restrict__ pd,
    const float* __restrict__ w_dist, const _Float16* __restrict__ Wt,
    const float* __restrict__ b_out, _Float16* __restrict__ R)
{
    __shared__ _Float16 As[128][72];
    __shared__ _Float16 Bs[128][72];
    __shared__ float fs[3][128];
    __shared__ float tps[C_];
    __shared__ float wds[3][C_];
    int bm = blockIdx.x, bn = blockIdx.y;
    int tid = threadIdx.x;

    if (tid < 128) {
        int d = pd[bm * 128 + tid];
        fs[0][tid] = log1pf(fmaxf((float)d, 0.f));
        fs[1][tid] = log1pf(fmaxf((float)(-d), 0.f));
        fs[2][tid] = (d == 0) ? 1.f : 0.f;
    }
    for (int i = tid; i < C_; i += 256) tps[i] = tp[(size_t)bm * C_ + i];
    for (int i = tid; i < 3 * C_; i += 256) wds[i >> 9][i & 511] = w_dist[i];
    __syncthreads();

    int wave = tid >> 6, lane = tid & 63;
    int wm = (wave >> 1) * 64, wn = (wave & 1) * 64;
    int mrow = lane & 15, kq = (lane >> 4) * 8;
    int srow  = tid >> 1;            // 0..127
    int khalf = (tid & 1) * 32;      // 0 / 32
    int lrow = tid >> 3, lcol = (tid & 7) * 8;   // Bs staging
    float f0 = fs[0][srow], f1 = fs[1][srow], f2 = fs[2][srow];

    f32x4 acc[4][4] = {};
    for (int k0 = 0; k0 < C_; k0 += 64) {
        // generate A-tile rows (s) x 64 k: 32 elements per thread
        _Float16 abuf[32];
#pragma unroll
        for (int kk = 0; kk < 32; ++kk) {
            int k = k0 + khalf + kk;
            float e = tps[k] + f0 * wds[0][k] + f1 * wds[1][k] + f2 * wds[2][k];
            e = e / (1.f + __expf(-e));
            abuf[kk] = (_Float16)e;
        }
#pragma unroll
        for (int v = 0; v < 4; ++v)
            *(f16x8*)&As[srow][khalf + v * 8] = *(const f16x8*)&abuf[v * 8];
        // stage Wt tile
#pragma unroll
        for (int p = 0; p < 4; ++p) {
            int r = p * 32 + lrow;
            *(f16x8*)&Bs[r][lcol] = *(const f16x8*)&Wt[(size_t)(bn * 128 + r) * C_ + k0 + lcol];
        }
        __syncthreads();
#pragma unroll
        for (int ks = 0; ks < 64; ks += 32) {
            f16x8 af[4], bfr[4];
#pragma unroll
            for (int i = 0; i < 4; ++i) af[i]  = *(const f16x8*)&As[wm + i * 16 + mrow][ks + kq];
#pragma unroll
            for (int j = 0; j < 4; ++j) bfr[j] = *(const f16x8*)&Bs[wn + j * 16 + mrow][ks + kq];
#pragma unroll
            for (int i = 0; i < 4; ++i)
#pragma unroll
                for (int j = 0; j < 4; ++j)
                    acc[i][j] = __builtin_amdgcn_mfma_f32_16x16x32_f16(af[i], bfr[j], acc[i][j], 0, 0, 0);
        }
        __syncthreads();
    }
    // C/D layout: col = lane&15, row = (lane>>4)*4 + reg
    int col = lane & 15, rb = (lane >> 4) * 4;
    const size_t arow0 = (size_t)bm * 128;
#pragma unroll
    for (int j = 0; j < 4; ++j) {
        int n = bn * 128 + wn + j * 16 + col;
        float bo = b_out[n];
#pragma unroll
        for (int i = 0; i < 4; ++i)
#pragma unroll
            for (int r = 0; r < 4; ++r) {
                size_t m = arow0 + wm + i * 16 + rb + r;
                R[m * C_ + n] = (_Float16)(acc[i][j][r] + bo);
            }
    }
}

// ---------------------------------------------------------------------------
// K4: out[b,d,h,t,s] = sum_f qk[b,d,h,t,f] * R[(b*T+t)*S+s][h*64+f]
// One block per (b,h,t, d-half): M=128(d) x N=128(s) x K=64(f).
// No LDS: MFMA fragments loaded directly from global (A: fp32->f16 cvt in regs,
// B: f16 rows are already in B-operand layout).
// ---------------------------------------------------------------------------
__global__ __launch_bounds__(256) void k_einsum(
    const float* __restrict__ qk, const _Float16* __restrict__ R,
    float* __restrict__ out)
{
    int bht  = blockIdx.x;          // b*H*T + h*T + t
    int dblk = blockIdx.y;          // 0 / 1
    int t = bht & 127;
    int h = (bht >> 7) & 7;
    int b = bht >> 10;
    int tid = threadIdx.x;
    int wave = tid >> 6, lane = tid & 63;
    int wm = (wave >> 1) * 64, wn = (wave & 1) * 64;
    int mrow = lane & 15, kq = (lane >> 4) * 8;

    const size_t HTF = (size_t)H_ * T_ * F_;     // 65536
    const float* qbase = qk + (size_t)b * D_ * HTF + (size_t)h * (T_ * F_)
                       + (size_t)t * F_ + (size_t)(dblk * 128) * HTF;
    const _Float16* rbase = R + ((size_t)(b * T_ + t) * S_) * C_ + h * 64;

    f32x4 acc[4][4] = {};
#pragma unroll
    for (int ks = 0; ks < 64; ks += 32) {
        f16x8 af[4], bfr[4];
#pragma unroll
        for (int i = 0; i < 4; ++i) {
            const float* p = qbase + (size_t)(wm + i * 16 + mrow) * HTF + ks + kq;
            float4 v0 = *(const float4*)p;
            float4 v1 = *(const float4*)(p + 4);
            f16x8 a;
            a[0] = (_Float16)v0.x; a[1] = (_Float16)v0.y;
            a[2] = (_Float16)v0.z; a[3] = (_Float16)v0.w;
            a[4] = (_Float16)v1.x; a[5] = (_Float16)v1.y;
            a[6] = (_Float16)v1.z; a[7] = (_Float16)v1.w;
            af[i] = a;
        }
#pragma unroll
        for (int j = 0; j < 4; ++j)
            bfr[j] = *(const f16x8*)(rbase + (size_t)(wn + j * 16 + mrow) * C_ + ks + kq);
#pragma unroll
        for (int i = 0; i < 4; ++i)
#pragma unroll
            for (int j = 0; j < 4; ++j)
                acc[i][j] = __builtin_amdgcn_mfma_f32_16x16x32_f16(af[i], bfr[j], acc[i][j], 0, 0, 0);
    }

    const size_t obase = (size_t)b * ((size_t)D_ * H_ * T_ * S_) + (size_t)h * (T_ * S_)
                       + (size_t)t * S_ + (size_t)(dblk * 128) * ((size_t)H_ * T_ * S_);
    int col = lane & 15, rb = (lane >> 4) * 4;
#pragma unroll
    for (int i = 0; i < 4; ++i)
#pragma unroll
        for (int r = 0; r < 4; ++r) {
            int dloc = wm + i * 16 + rb + r;
            size_t o = obase + (size_t)dloc * ((size_t)H_ * T_ * S_);
#pragma unroll
            for (int j = 0; j < 4; ++j)
                out[o + wn + j * 16 + col] = acc[i][j][r];
        }
}

// ---------------------------------------------------------------------------
extern "C" void kernel_launch(void* const* d_in, const int* in_sizes, int n_in,
                              void* d_out, int out_size, void* d_ws, size_t ws_size,
                              hipStream_t stream) {
    (void)in_sizes; (void)n_in; (void)out_size; (void)ws_size;
    const float* qk     = (const float*)d_in[0];
    const float* temb   = (const float*)d_in[1];
    const int*   pd     = (const int*)d_in[2];
    const float* w_dist = (const float*)d_in[3];
    const float* b_dist = (const float*)d_in[4];
    const float* w_time = (const float*)d_in[5];
    const float* b_time = (const float*)d_in[6];
    const float* w_out  = (const float*)d_in[7];
    const float* b_out  = (const float*)d_in[8];
    float* out = (float*)d_out;

    char* ws = (char*)d_ws;
    float*     tp = (float*)ws;                         // 512 KB
    _Float16*  Wt = (_Float16*)(ws + 512 * 1024);       // 512 KB
    _Float16*  R  = (_Float16*)(ws + 1024 * 1024);      // 32 MB

    k_time_proj<<<dim3(B_ * T_ / 2), dim3(256), 0, stream>>>(temb, w_time, b_time, b_dist, tp);
    k_wt<<<dim3(8, 8), dim3(256), 0, stream>>>(w_out, Wt);
    k_rpe_gemm<<<dim3(256, 4), dim3(256), 0, stream>>>(tp, pd, w_dist, Wt, b_out, R);
    k_einsum<<<dim3(B_ * H_ * T_, 2), dim3(256), 0, stream>>>(qk, R, out);
}

// Round 3
// 537.614 us; speedup vs baseline: 1.0077x; 1.0077x over previous
//
#include <hip/hip_runtime.h>
#include <hip/hip_bf16.h>

#define B_  2
#define D_  256
#define H_  8
#define T_  128
#define S_  128
#define F_  64
#define C_  512
#define TE_ 512

typedef _Float16 f16x8 __attribute__((ext_vector_type(8)));
typedef _Float16 f16x4 __attribute__((ext_vector_type(4)));
typedef float    f32x4 __attribute__((ext_vector_type(4)));

// ---------------------------------------------------------------------------
// K1: time_proj[b*T+t][c] = temb[b,t,:] @ w_time[:,c] + b_time[c] + b_dist[c]
// 64 blocks x 256 threads, 4 rows per block, 2 cols per thread:
// 8 FMA per 2 w-loads -> compute-dense, latency-tolerant.
// ---------------------------------------------------------------------------
__global__ __launch_bounds__(256) void k_time_proj(
    const float* __restrict__ temb, const float* __restrict__ w_time,
    const float* __restrict__ b_time, const float* __restrict__ b_dist,
    float* __restrict__ tp)
{
    int row0 = blockIdx.x * 4;
    int tid  = threadIdx.x;
    __shared__ float te[4][TE_];
    for (int i = tid; i < 4 * TE_; i += 256)
        te[i >> 9][i & 511] = temb[(size_t)row0 * TE_ + i];
    __syncthreads();
    int c0 = tid, c1 = tid + 256;
    float bias0 = b_time[c0] + b_dist[c0];
    float bias1 = b_time[c1] + b_dist[c1];
    float a[4][2];
#pragma unroll
    for (int r = 0; r < 4; ++r) { a[r][0] = bias0; a[r][1] = bias1; }
#pragma unroll 4
    for (int e = 0; e < TE_; ++e) {
        float w0 = w_time[(size_t)e * C_ + c0];
        float w1 = w_time[(size_t)e * C_ + c1];
#pragma unroll
        for (int r = 0; r < 4; ++r) {
            float t = te[r][e];
            a[r][0] += t * w0;
            a[r][1] += t * w1;
        }
    }
#pragma unroll
    for (int r = 0; r < 4; ++r) {
        tp[(size_t)(row0 + r) * C_ + c0] = a[r][0];
        tp[(size_t)(row0 + r) * C_ + c1] = a[r][1];
    }
}

// ---------------------------------------------------------------------------
// K2: Wt[n][k] = f16(w_out[k][n])  via LDS 64x64 transpose
// ---------------------------------------------------------------------------
__global__ __launch_bounds__(256) void k_wt(
    const float* __restrict__ w_out, _Float16* __restrict__ Wt)
{
    __shared__ float tile[64][65];
    int bn = blockIdx.x;
    int bk = blockIdx.y;
    int tx = threadIdx.x & 63;
    int ty = threadIdx.x >> 6;
#pragma unroll
    for (int p = 0; p < 16; ++p) {
        int row = p * 4 + ty;
        tile[row][tx] = w_out[(size_t)(bk * 64 + row) * C_ + bn * 64 + tx];
    }
    __syncthreads();
#pragma unroll
    for (int p = 0; p < 16; ++p) {
        int row = p * 4 + ty;
        Wt[(size_t)(bn * 64 + row) * C_ + bk * 64 + tx] = (_Float16)tile[tx][row];
    }
}

// ---------------------------------------------------------------------------
// K3: A[row][c] = f16( silu( tp[bt][c] + f0*w0[c] + f1*w1[c] + f2*w2[c] ) )
// 4096 blocks x 256 threads, 8 rows/block, 16 channels/thread.
// ---------------------------------------------------------------------------
__global__ __launch_bounds__(256) void k_embed_silu(
    const float* __restrict__ tp, const int* __restrict__ pd,
    const float* __restrict__ w_dist, _Float16* __restrict__ A)
{
    int row = blockIdx.x * 8 + (threadIdx.x >> 5);
    int bt  = row >> 7;
    int d   = pd[row];
    float f0 = log1pf(fmaxf((float)d, 0.f));
    float f1 = log1pf(fmaxf((float)(-d), 0.f));
    float f2 = (d == 0) ? 1.f : 0.f;
    int c0 = (threadIdx.x & 31) * 16;
    _Float16 buf[16];
#pragma unroll
    for (int v = 0; v < 4; ++v) {
        int c = c0 + v * 4;
        float4 t4 = *(const float4*)&tp[(size_t)bt * C_ + c];
        float4 w0 = *(const float4*)&w_dist[c];
        float4 w1 = *(const float4*)&w_dist[C_ + c];
        float4 w2 = *(const float4*)&w_dist[2 * C_ + c];
        float e0 = t4.x + f0 * w0.x + f1 * w1.x + f2 * w2.x;
        float e1 = t4.y + f0 * w0.y + f1 * w1.y + f2 * w2.y;
        float e2 = t4.z + f0 * w0.z + f1 * w1.z + f2 * w2.z;
        float e3 = t4.w + f0 * w0.w + f1 * w1.w + f2 * w2.w;
        buf[v * 4 + 0] = (_Float16)(e0 / (1.f + __expf(-e0)));
        buf[v * 4 + 1] = (_Float16)(e1 / (1.f + __expf(-e1)));
        buf[v * 4 + 2] = (_Float16)(e2 / (1.f + __expf(-e2)));
        buf[v * 4 + 3] = (_Float16)(e3 / (1.f + __expf(-e3)));
    }
    *(f16x8*)&A[(size_t)row * C_ + c0]     = *(const f16x8*)&buf[0];
    *(f16x8*)&A[(size_t)row * C_ + c0 + 8] = *(const f16x8*)&buf[8];
}

// ---------------------------------------------------------------------------
// K4: R = A(32768x512) @ Wt^T(512x512) + b_out   -> f16   (round-1 version)
// ---------------------------------------------------------------------------
__global__ __launch_bounds__(256) void k_gemm_R(
    const _Float16* __restrict__ A, const _Float16* __restrict__ Wt,
    const float* __restrict__ b_out, _Float16* __restrict__ R)
{
    const int K = 512, N = 512;
    __shared__ _Float16 As[128][72];
    __shared__ _Float16 Bs[128][72];
    int bm = blockIdx.x, bn = blockIdx.y;
    int tid = threadIdx.x;
    int wave = tid >> 6, lane = tid & 63;
    int wm = (wave >> 1) * 64, wn = (wave & 1) * 64;
    int mrow = lane & 15, kq = (lane >> 4) * 8;
    int lrow = tid >> 3, lcol = (tid & 7) * 8;
    const size_t arow0 = (size_t)bm * 128;
    f32x4 acc[4][4] = {};
    for (int k0 = 0; k0 < K; k0 += 64) {
#pragma unroll
        for (int p = 0; p < 4; ++p) {
            int r = p * 32 + lrow;
            *(f16x8*)&As[r][lcol] = *(const f16x8*)&A[(arow0 + r) * K + k0 + lcol];
            *(f16x8*)&Bs[r][lcol] = *(const f16x8*)&Wt[(size_t)(bn * 128 + r) * K + k0 + lcol];
        }
        __syncthreads();
#pragma unroll
        for (int ks = 0; ks < 64; ks += 32) {
            f16x8 af[4], bfr[4];
#pragma unroll
            for (int i = 0; i < 4; ++i) af[i]  = *(const f16x8*)&As[wm + i * 16 + mrow][ks + kq];
#pragma unroll
            for (int j = 0; j < 4; ++j) bfr[j] = *(const f16x8*)&Bs[wn + j * 16 + mrow][ks + kq];
#pragma unroll
            for (int i = 0; i < 4; ++i)
#pragma unroll
                for (int j = 0; j < 4; ++j)
                    acc[i][j] = __builtin_amdgcn_mfma_f32_16x16x32_f16(af[i], bfr[j], acc[i][j], 0, 0, 0);
        }
        __syncthreads();
    }
    int col = lane & 15, rb = (lane >> 4) * 4;
#pragma unroll
    for (int j = 0; j < 4; ++j) {
        int n = bn * 128 + wn + j * 16 + col;
        float bo = b_out[n];
#pragma unroll
        for (int i = 0; i < 4; ++i)
#pragma unroll
            for (int r = 0; r < 4; ++r) {
                size_t m = arow0 + wm + i * 16 + rb + r;
                R[m * N + n] = (_Float16)(acc[i][j][r] + bo);
            }
    }
}

// ---------------------------------------------------------------------------
// K5: out[b,d,h,t,s] = sum_f qk[b,d,h,t,f] * R[(b*T+t)*S+s][h*64+f]
// No-LDS MFMA, nontemporal qk loads + out stores (write-once data skips L2).
// ---------------------------------------------------------------------------
__global__ __launch_bounds__(256) void k_einsum(
    const float* __restrict__ qk, const _Float16* __restrict__ R,
    float* __restrict__ out)
{
    int bht  = blockIdx.x;
    int dblk = blockIdx.y;
    int t = bht & 127;
    int h = (bht >> 7) & 7;
    int b = bht >> 10;
    int tid = threadIdx.x;
    int wave = tid >> 6, lane = tid & 63;
    int wm = (wave >> 1) * 64, wn = (wave & 1) * 64;
    int mrow = lane & 15, kq = (lane >> 4) * 8;

    const size_t HTF = (size_t)H_ * T_ * F_;
    const float* qbase = qk + (size_t)b * D_ * HTF + (size_t)h * (T_ * F_)
                       + (size_t)t * F_ + (size_t)(dblk * 128) * HTF;
    const _Float16* rbase = R + ((size_t)(b * T_ + t) * S_) * C_ + h * 64;

    f32x4 acc[4][4] = {};
#pragma unroll
    for (int ks = 0; ks < 64; ks += 32) {
        f16x8 af[4], bfr[4];
#pragma unroll
        for (int i = 0; i < 4; ++i) {
            const f32x4* p = (const f32x4*)(qbase + (size_t)(wm + i * 16 + mrow) * HTF + ks + kq);
            f32x4 v0 = __builtin_nontemporal_load(p);
            f32x4 v1 = __builtin_nontemporal_load(p + 1);
            f16x8 a;
            a[0] = (_Float16)v0[0]; a[1] = (_Float16)v0[1];
            a[2] = (_Float16)v0[2]; a[3] = (_Float16)v0[3];
            a[4] = (_Float16)v1[0]; a[5] = (_Float16)v1[1];
            a[6] = (_Float16)v1[2]; a[7] = (_Float16)v1[3];
            af[i] = a;
        }
#pragma unroll
        for (int j = 0; j < 4; ++j)
            bfr[j] = *(const f16x8*)(rbase + (size_t)(wn + j * 16 + mrow) * C_ + ks + kq);
#pragma unroll
        for (int i = 0; i < 4; ++i)
#pragma unroll
            for (int j = 0; j < 4; ++j)
                acc[i][j] = __builtin_amdgcn_mfma_f32_16x16x32_f16(af[i], bfr[j], acc[i][j], 0, 0, 0);
    }

    const size_t obase = (size_t)b * ((size_t)D_ * H_ * T_ * S_) + (size_t)h * (T_ * S_)
                       + (size_t)t * S_ + (size_t)(dblk * 128) * ((size_t)H_ * T_ * S_);
    int col = lane & 15, rb = (lane >> 4) * 4;
#pragma unroll
    for (int i = 0; i < 4; ++i)
#pragma unroll
        for (int r = 0; r < 4; ++r) {
            int dloc = wm + i * 16 + rb + r;
            size_t o = obase + (size_t)dloc * ((size_t)H_ * T_ * S_);
#pragma unroll
            for (int j = 0; j < 4; ++j)
                __builtin_nontemporal_store(acc[i][j][r], &out[o + wn + j * 16 + col]);
        }
}

// ---------------------------------------------------------------------------
extern "C" void kernel_launch(void* const* d_in, const int* in_sizes, int n_in,
                              void* d_out, int out_size, void* d_ws, size_t ws_size,
                              hipStream_t stream) {
    (void)in_sizes; (void)n_in; (void)out_size; (void)ws_size;
    const float* qk     = (const float*)d_in[0];
    const float* temb   = (const float*)d_in[1];
    const int*   pd     = (const int*)d_in[2];
    const float* w_dist = (const float*)d_in[3];
    const float* b_dist = (const float*)d_in[4];
    const float* w_time = (const float*)d_in[5];
    const float* b_time = (const float*)d_in[6];
    const float* w_out  = (const float*)d_in[7];
    const float* b_out  = (const float*)d_in[8];
    float* out = (float*)d_out;

    char* ws = (char*)d_ws;
    float*     tp = (float*)ws;                         // 512 KB
    _Float16*  Wt = (_Float16*)(ws + 512 * 1024);       // 512 KB
    _Float16*  A  = (_Float16*)(ws + 1024 * 1024);      // 32 MB
    _Float16*  R  = (_Float16*)(ws + 1024 * 1024 + 33554432); // 32 MB

    k_time_proj<<<dim3(B_ * T_ / 4), dim3(256), 0, stream>>>(temb, w_time, b_time, b_dist, tp);
    k_wt<<<dim3(8, 8), dim3(256), 0, stream>>>(w_out, Wt);
    k_embed_silu<<<dim3(B_ * T_ * S_ / 8), dim3(256), 0, stream>>>(tp, pd, w_dist, A);
    k_gemm_R<<<dim3(256, 4), dim3(256), 0, stream>>>(A, Wt, b_out, R);
    k_einsum<<<dim3(B_ * H_ * T_, 2), dim3(256), 0, stream>>>(qk, R, out);
}